// Round 3
// baseline (2896.908 us; speedup 1.0000x reference)
//
#include <hip/hip_runtime.h>

#define N 4096
#define D 10000
#define D4 2500          // D/4
#define C 10
#define NB 16            // number of 256-step blocks
#define B 256            // steps per block

// ---- workspace layout (float offsets) ----
#define AM_OFF    0                          // [C*D] = 100000
#define GLOC_OFF  100096                     // [16][256][256] = 1048576
#define S_OFF     (GLOC_OFF + NB*B*B)        // [B*C] = 2560
#define HV2_OFF   (S_OFF + B*C)              // [N]
#define AN_OFF    (HV2_OFF + N)              // [16] running ||am_c||^2
#define ANF_OFF   (AN_OFF + 16)              // [16] final  ||am_c||^2
#define PRED_OFF  (ANF_OFF + 16)             // [N] ints
#define WRONG_OFF (PRED_OFF + N)             // [N] ints
#define MIST_OFF  (WRONG_OFF + N)            // [1] int

// ---------------- build_am: segment-sum, float4, register accumulate + atomics ------------
__global__ __launch_bounds__(256) void build_am_kernel(float* __restrict__ am,
        const float* __restrict__ X, const int* __restrict__ labels){
    int d4 = blockIdx.x*256 + threadIdx.x;
    if (d4 >= D4) return;
    int i0 = blockIdx.y * (N/16);
    const float4* X4 = (const float4*)X;
    float4 acc[C];
    #pragma unroll
    for (int c=0;c<C;c++) acc[c] = make_float4(0.f,0.f,0.f,0.f);
    for (int i=i0; i<i0+(N/16); ++i){
        int lab = labels[i];
        float4 x = X4[(size_t)i*D4 + d4];
        #pragma unroll
        for (int c=0;c<C;c++){
            float m = (lab==c) ? 1.f : 0.f;
            acc[c].x += m*x.x; acc[c].y += m*x.y; acc[c].z += m*x.z; acc[c].w += m*x.w;
        }
    }
    #pragma unroll
    for (int c=0;c<C;c++){
        float* p = &am[(size_t)c*D + d4*4];
        atomicAdd(p+0, acc[c].x); atomicAdd(p+1, acc[c].y);
        atomicAdd(p+2, acc[c].z); atomicAdd(p+3, acc[c].w);
    }
}

// ---------------- row sum-of-squares of am -> out[c] ----------------
__global__ __launch_bounds__(256) void rownorm2_kernel(const float* __restrict__ am,
        float* __restrict__ out){
    int c = blockIdx.x, t = threadIdx.x;
    const float4* a4 = (const float4*)(am + (size_t)c*D);
    float p = 0.f;
    for (int d=t; d<D4; d+=256){ float4 v = a4[d]; p += v.x*v.x+v.y*v.y+v.z*v.z+v.w*v.w; }
    #pragma unroll
    for (int off=32; off>=1; off>>=1) p += __shfl_down(p, off);
    __shared__ float wsum[4];
    int wid = t>>6, lane = t&63;
    if (lane==0) wsum[wid]=p;
    __syncthreads();
    if (t==0) out[c] = wsum[0]+wsum[1]+wsum[2]+wsum[3];
}

// ---------------- block-diagonal Gram tiles (fp32, LDS-tiled, K-split, atomic accumulate) ----
__global__ __launch_bounds__(256) void gram_kernel(const float* __restrict__ X,
        float* __restrict__ Gloc){
    __shared__ float Asm[32][68];   // transposed: [dd][row]
    __shared__ float Bsm[32][68];
    int bx = blockIdx.x;
    int k  = blockIdx.y;
    int p  = bx % 10;               // upper-triangle 64x64 tile pair
    int z  = bx / 10;               // K-split 0..7
    int ti = (p<4)?0:(p<7)?1:(p<9)?2:3;
    int st = (ti==0)?0:(ti==1)?4:(ti==2)?7:9;
    int tj = ti + (p - st);
    int rowA = k*B + ti*64;
    int rowB = k*B + tj*64;
    int t = threadIdx.x;
    int tx = t & 15, ty = t >> 4;
    float acc[4][4];
    #pragma unroll
    for (int i=0;i<4;i++)
        #pragma unroll
        for (int j=0;j<4;j++) acc[i][j]=0.f;

    for (int ch = z; ch*32 < D; ch += 8){
        int dbase = ch*32;
        int valid = D - dbase; if (valid > 32) valid = 32;   // 32 or 16, always mult of 4
        // float4 staging: 64 rows x 32 dd = 512 float4 per matrix, 2 per thread
        #pragma unroll
        for (int f0 = 0; f0 < 512; f0 += 256){
            int f = f0 + t;
            int row = f >> 3, q = f & 7;
            float4 a = make_float4(0,0,0,0), b = make_float4(0,0,0,0);
            if (q*4 < valid){
                a = *(const float4*)&X[(size_t)(rowA + row)*D + dbase + q*4];
                b = *(const float4*)&X[(size_t)(rowB + row)*D + dbase + q*4];
            }
            Asm[q*4+0][row]=a.x; Asm[q*4+1][row]=a.y; Asm[q*4+2][row]=a.z; Asm[q*4+3][row]=a.w;
            Bsm[q*4+0][row]=b.x; Bsm[q*4+1][row]=b.y; Bsm[q*4+2][row]=b.z; Bsm[q*4+3][row]=b.w;
        }
        __syncthreads();
        #pragma unroll 4
        for (int dd=0; dd<32; ++dd){
            const float4 av = *(const float4*)&Asm[dd][ty*4];
            const float4 bv = *(const float4*)&Bsm[dd][tx*4];
            float a4[4] = {av.x, av.y, av.z, av.w};
            float b4[4] = {bv.x, bv.y, bv.z, bv.w};
            #pragma unroll
            for (int i=0;i<4;i++)
                #pragma unroll
                for (int j=0;j<4;j++) acc[i][j] += a4[i]*b4[j];
        }
        __syncthreads();
    }
    float* G = Gloc + (size_t)k*B*B;
    int abase = ti*64 + ty*4;
    int bbase = tj*64 + tx*4;
    #pragma unroll
    for (int i=0;i<4;i++)
        #pragma unroll
        for (int j=0;j<4;j++)
            atomicAdd(&G[(abase+i)*B + (bbase+j)], acc[i][j]);
}

// ---------------- S[j][c] = am_c . hv_j (+ fused ||hv||^2) for one 256-block, float4 -------
__global__ __launch_bounds__(256) void s_kernel(const float* __restrict__ am,
        const float* __restrict__ X, float* __restrict__ S, float* __restrict__ hv2, int k){
    int j = blockIdx.x;
    int gj = k*B + j;
    int t = threadIdx.x;
    const float4* xr = (const float4*)(X + (size_t)gj*D);
    const float4* a4 = (const float4*)am;
    float p[C+1];
    #pragma unroll
    for (int v=0;v<C+1;v++) p[v]=0.f;
    for (int d=t; d<D4; d+=256){
        float4 x = xr[d];
        p[C] += x.x*x.x + x.y*x.y + x.z*x.z + x.w*x.w;
        #pragma unroll
        for (int c=0;c<C;c++){
            float4 a = a4[(size_t)c*D4 + d];
            p[c] += x.x*a.x + x.y*a.y + x.z*a.z + x.w*a.w;
        }
    }
    __shared__ float red[(C+1)*4];
    int wid=t>>6, lane=t&63;
    #pragma unroll
    for (int v=0; v<C+1; ++v){
        float x = p[v];
        #pragma unroll
        for (int off=32; off>=1; off>>=1) x += __shfl_down(x, off);
        if (lane==0) red[v*4+wid] = x;
    }
    __syncthreads();
    if (t < C+1){
        float r = red[t*4+0]+red[t*4+1]+red[t*4+2]+red[t*4+3];
        if (t < C) S[j*C + t] = r;
        else hv2[gj] = r;
    }
}

// ---------------- sequential 256-step replay: single wave, 8-deep G prefetch ----------------
__global__ __launch_bounds__(64) void seq_kernel(const float* __restrict__ S,
        const float* __restrict__ G,        // this block's [256][256] Gram
        const float* __restrict__ hv2, const int* __restrict__ labels,
        float* __restrict__ amnorm2, int* __restrict__ predArr, int* __restrict__ wrongArr,
        int* __restrict__ mistakes, int k){
    int lane = threadIdx.x;
    int base = k*B;
    float s[4][C];
    float h2o[4]; int labo[4];
    #pragma unroll
    for (int q=0;q<4;q++){
        int j = q*64 + lane;
        #pragma unroll
        for (int c=0;c<C;c++) s[q][c] = S[j*C+c];
        h2o[q] = hv2[base + j];
        labo[q] = labels[base + j];
    }
    float an[C], rstd[C];
    #pragma unroll
    for (int c=0;c<C;c++){ an[c] = amnorm2[c]; rstd[c] = rsqrtf(an[c]); }

    int mycnt = 0;
    int myPred[4], myWrong[4];
    #pragma unroll
    for (int q=0;q<4;q++){ myPred[q]=0; myWrong[q]=0; }

    // 8-deep circular register prefetch of G rows (static slot indexing via unroll)
    float g[8][4];
    #pragma unroll
    for (int r=0;r<8;r++)
        #pragma unroll
        for (int sl=0;sl<4;sl++) g[r][sl] = G[(size_t)r*B + sl*64 + lane];

    #pragma unroll
    for (int q=0;q<4;q++){
        for (int jj8=0; jj8<8; ++jj8){
            #pragma unroll
            for (int u=0; u<8; ++u){
                int jj = jj8*8 + u;
                int j  = q*64 + jj;
                float gcur[4];
                #pragma unroll
                for (int sl=0;sl<4;sl++) gcur[sl] = g[u][sl];
                if (j+8 < B){
                    #pragma unroll
                    for (int sl=0;sl<4;sl++) g[u][sl] = G[(size_t)(j+8)*B + sl*64 + lane];
                }
                // each lane computes the decision for ITS OWN sample from its own registers
                float best = s[q][0]*rstd[0]; int bi=0; float braw = s[q][0];
                #pragma unroll
                for (int c=1;c<C;c++){
                    float v = s[q][c]*rstd[c];
                    if (v>best){best=v;bi=c;braw=s[q][c];}
                }
                int labme = labo[q];
                float slv = s[q][0];
                #pragma unroll
                for (int c=1;c<C;c++) slv = (c==labme)? s[q][c] : slv;
                int wrongme = (bi != labme) ? 1 : 0;
                if (lane == jj){ myPred[q]=bi; myWrong[q]=wrongme; }
                // broadcast owner's decision: 4 shuffles
                int   pk    = __shfl(bi | (labme<<8) | (wrongme<<16), jj);
                float brawB = __shfl(braw, jj);
                float slvB  = __shfl(slv,  jj);
                float h2b   = __shfl(h2o[q], jj);
                int biB = pk & 255, labB = (pk>>8) & 255, wrongB = (pk>>16) & 1;
                if (wrongB){
                    mycnt++;
                    float anp = an[0], anl = an[0];
                    #pragma unroll
                    for (int c=1;c<C;c++){ anp = (c==biB)? an[c]:anp; anl = (c==labB)? an[c]:anl; }
                    float anp_new = anp - 2.f*brawB + h2b;   // ||am_pred - hv||^2
                    float anl_new = anl + 2.f*slvB  + h2b;   // ||am_lab  + hv||^2
                    float rp = rsqrtf(anp_new), rl = rsqrtf(anl_new);
                    #pragma unroll
                    for (int c=0;c<C;c++){
                        an[c]   = (c==biB)? anp_new : (c==labB)? anl_new : an[c];
                        rstd[c] = (c==biB)? rp      : (c==labB)? rl      : rstd[c];
                    }
                    #pragma unroll
                    for (int c=0;c<C;c++){
                        float sg = (c==biB)? -1.f : (c==labB)? 1.f : 0.f;
                        #pragma unroll
                        for (int sl=0;sl<4;sl++) s[sl][c] += sg * gcur[sl];
                    }
                }
            }
        }
    }
    #pragma unroll
    for (int q=0;q<4;q++){
        predArr[base + q*64 + lane]  = myPred[q];
        wrongArr[base + q*64 + lane] = myWrong[q];
    }
    if (lane==0){
        atomicAdd(mistakes, mycnt);
        #pragma unroll
        for (int c=0;c<C;c++) amnorm2[c] = an[c];
    }
}

// ---------------- fold the block's +/-hv corrections into am: atomic-free, float4 ----------
__global__ __launch_bounds__(256) void apply_kernel(float* __restrict__ am,
        const float* __restrict__ X, const int* __restrict__ labels,
        const int* __restrict__ predA, const int* __restrict__ wrongA, int k){
    int d4 = blockIdx.x*256 + threadIdx.x;
    if (d4 >= D4) return;
    const float4* X4 = (const float4*)X;
    float4 delta[C];
    #pragma unroll
    for (int c=0;c<C;c++) delta[c] = make_float4(0.f,0.f,0.f,0.f);
    for (int j=0;j<B;j++){
        int gj = k*B + j;
        float w = wrongA[gj] ? 1.f : 0.f;        // uniform scalar
        int p = predA[gj], l = labels[gj];       // uniform
        float4 x = X4[(size_t)gj*D4 + d4];       // unconditional, pipelines well
        #pragma unroll
        for (int c=0;c<C;c++){
            float coef = w * ((c==p)? -1.f : (c==l)? 1.f : 0.f);
            delta[c].x += coef*x.x; delta[c].y += coef*x.y;
            delta[c].z += coef*x.z; delta[c].w += coef*x.w;
        }
    }
    float4* am4 = (float4*)am;
    #pragma unroll
    for (int c=0;c<C;c++){
        float4 v = am4[(size_t)c*D4 + d4];
        v.x += delta[c].x; v.y += delta[c].y; v.z += delta[c].z; v.w += delta[c].w;
        am4[(size_t)c*D4 + d4] = v;
    }
}

// ---------------- final predict: 4 rows/WG, float4, am reuse in registers ----------------
__global__ __launch_bounds__(256) void predict_kernel(const float* __restrict__ am,
        const float* __restrict__ X, const float* __restrict__ anf, float* __restrict__ outPred){
    int i0 = blockIdx.x*4, t = threadIdx.x;
    const float4* a4 = (const float4*)am;
    const float4* X4 = (const float4*)X;
    float p[4][C];
    #pragma unroll
    for (int r=0;r<4;r++)
        #pragma unroll
        for (int c=0;c<C;c++) p[r][c]=0.f;
    for (int d=t; d<D4; d+=256){
        float4 x0 = X4[(size_t)(i0+0)*D4 + d];
        float4 x1 = X4[(size_t)(i0+1)*D4 + d];
        float4 x2 = X4[(size_t)(i0+2)*D4 + d];
        float4 x3 = X4[(size_t)(i0+3)*D4 + d];
        #pragma unroll
        for (int c=0;c<C;c++){
            float4 a = a4[(size_t)c*D4 + d];
            p[0][c] += x0.x*a.x + x0.y*a.y + x0.z*a.z + x0.w*a.w;
            p[1][c] += x1.x*a.x + x1.y*a.y + x1.z*a.z + x1.w*a.w;
            p[2][c] += x2.x*a.x + x2.y*a.y + x2.z*a.z + x2.w*a.w;
            p[3][c] += x3.x*a.x + x3.y*a.y + x3.z*a.z + x3.w*a.w;
        }
    }
    __shared__ float red[4][C][4];
    int wid=t>>6, lane=t&63;
    #pragma unroll
    for (int r=0;r<4;r++)
        #pragma unroll
        for (int c=0;c<C;c++){
            float x = p[r][c];
            #pragma unroll
            for (int off=32; off>=1; off>>=1) x += __shfl_down(x, off);
            if (lane==0) red[r][c][wid] = x;
        }
    __syncthreads();
    if (t < 4){
        float best = -3.4e38f; int bi = 0;
        #pragma unroll
        for (int c=0;c<C;c++){
            float dot = red[t][c][0]+red[t][c][1]+red[t][c][2]+red[t][c][3];
            float v = dot * rsqrtf(anf[c]);
            if (v > best){ best = v; bi = c; }
        }
        outPred[i0 + t] = (float)bi;
    }
}

// ---------------- am copy + mistakes scalar ----------------
__global__ __launch_bounds__(256) void finalize_kernel(const float* __restrict__ am,
        const int* __restrict__ mistakes, float* __restrict__ out){
    int i = blockIdx.x*256 + threadIdx.x;
    if (i < C*D) out[i] = am[i];
    if (i == 0) out[C*D + N] = (float)(*mistakes);
}

extern "C" void kernel_launch(void* const* d_in, const int* in_sizes, int n_in,
                              void* d_out, int out_size, void* d_ws, size_t ws_size,
                              hipStream_t stream){
    const float* X      = (const float*)d_in[0];
    const int*   labels = (const int*)d_in[1];
    float* ws   = (float*)d_ws;
    float* am   = ws + AM_OFF;
    float* Gloc = ws + GLOC_OFF;
    float* S    = ws + S_OFF;
    float* hv2  = ws + HV2_OFF;
    float* an   = ws + AN_OFF;
    float* anf  = ws + ANF_OFF;
    int*   predA  = (int*)(ws + PRED_OFF);
    int*   wrongA = (int*)(ws + WRONG_OFF);
    int*   mist   = (int*)(ws + MIST_OFF);
    float* out = (float*)d_out;

    hipMemsetAsync(am,   0, (size_t)C*D*sizeof(float), stream);
    hipMemsetAsync(Gloc, 0, (size_t)NB*B*B*sizeof(float), stream);
    hipMemsetAsync(mist, 0, sizeof(int), stream);

    build_am_kernel<<<dim3(10,16), 256, 0, stream>>>(am, X, labels);
    rownorm2_kernel<<<C, 256, 0, stream>>>(am, an);
    gram_kernel<<<dim3(80,NB), 256, 0, stream>>>(X, Gloc);

    for (int k=0;k<NB;k++){
        s_kernel<<<B, 256, 0, stream>>>(am, X, S, hv2, k);
        seq_kernel<<<1, 64, 0, stream>>>(S, Gloc + (size_t)k*B*B, hv2, labels,
                                         an, predA, wrongA, mist, k);
        apply_kernel<<<10, 256, 0, stream>>>(am, X, labels, predA, wrongA, k);
    }

    rownorm2_kernel<<<C, 256, 0, stream>>>(am, anf);
    predict_kernel<<<N/4, 256, 0, stream>>>(am, X, anf, out + (size_t)C*D);
    finalize_kernel<<<(C*D + 255)/256 + 1, 256, 0, stream>>>(am, mist, out);
}

// Round 4
// 1594.568 us; speedup vs baseline: 1.8167x; 1.8167x over previous
//
#include <hip/hip_runtime.h>

#define N 4096
#define D 10000
#define D4 2500          // D/4
#define C 10
#define NB 16            // number of 256-step blocks
#define B 256            // steps per block

// ---- workspace layout (float offsets) ----
#define AM_OFF    0                          // [C*D] = 100000
#define GLOC_OFF  100096                     // [16][256][256] = 1048576
#define S_OFF     (GLOC_OFF + NB*B*B)        // [B*C] = 2560
#define HV2_OFF   (S_OFF + B*C)              // [N]
#define AN_OFF    (HV2_OFF + N)              // [16] running ||am_c||^2
#define ANF_OFF   (AN_OFF + 16)              // [16] final  ||am_c||^2
#define WLIST_OFF (ANF_OFF + 16)             // [NB*B] ints: packed idx|pred<<8|lab<<12
#define NWRONG_OFF (WLIST_OFF + NB*B)        // [NB] ints
#define MIST_OFF  (NWRONG_OFF + NB)          // [1] int

// ---------------- build_am: segment-sum, float4, register accumulate + atomics ------------
__global__ __launch_bounds__(256) void build_am_kernel(float* __restrict__ am,
        const float* __restrict__ X, const int* __restrict__ labels){
    int d4 = blockIdx.x*256 + threadIdx.x;
    if (d4 >= D4) return;
    int i0 = blockIdx.y * (N/16);
    const float4* X4 = (const float4*)X;
    float4 acc[C];
    #pragma unroll
    for (int c=0;c<C;c++) acc[c] = make_float4(0.f,0.f,0.f,0.f);
    for (int i=i0; i<i0+(N/16); ++i){
        int lab = labels[i];
        float4 x = X4[(size_t)i*D4 + d4];
        #pragma unroll
        for (int c=0;c<C;c++){
            float m = (lab==c) ? 1.f : 0.f;
            acc[c].x += m*x.x; acc[c].y += m*x.y; acc[c].z += m*x.z; acc[c].w += m*x.w;
        }
    }
    #pragma unroll
    for (int c=0;c<C;c++){
        float* p = &am[(size_t)c*D + d4*4];
        atomicAdd(p+0, acc[c].x); atomicAdd(p+1, acc[c].y);
        atomicAdd(p+2, acc[c].z); atomicAdd(p+3, acc[c].w);
    }
}

// ---------------- row sum-of-squares of am -> out[c] ----------------
__global__ __launch_bounds__(256) void rownorm2_kernel(const float* __restrict__ am,
        float* __restrict__ out){
    int c = blockIdx.x, t = threadIdx.x;
    const float4* a4 = (const float4*)(am + (size_t)c*D);
    float p = 0.f;
    for (int d=t; d<D4; d+=256){ float4 v = a4[d]; p += v.x*v.x+v.y*v.y+v.z*v.z+v.w*v.w; }
    #pragma unroll
    for (int off=32; off>=1; off>>=1) p += __shfl_down(p, off);
    __shared__ float wsum[4];
    int wid = t>>6, lane = t&63;
    if (lane==0) wsum[wid]=p;
    __syncthreads();
    if (t==0) out[c] = wsum[0]+wsum[1]+wsum[2]+wsum[3];
}

// ---------------- block-diagonal Gram tiles (fp32, LDS XOR-swizzled, K-split) --------------
// LDS col swizzle: logical col c of row dd stored at physical c ^ (((dd>>2)&7)<<3).
// Writes: bank = (24q + 4i + row) % 32 -> 32 banks, 2-way (free, m136).
// Reads: XOR permutes cols within 64-set -> same bank multiset as before (free).
__global__ __launch_bounds__(256) void gram_kernel(const float* __restrict__ X,
        float* __restrict__ Gloc){
    __shared__ float Asm[32][68];   // transposed: [dd][row], swizzled
    __shared__ float Bsm[32][68];
    int bx = blockIdx.x;
    int k  = blockIdx.y;
    int p  = bx % 10;               // upper-triangle 64x64 tile pair
    int z  = bx / 10;               // K-split 0..7
    int ti = (p<4)?0:(p<7)?1:(p<9)?2:3;
    int st = (ti==0)?0:(ti==1)?4:(ti==2)?7:9;
    int tj = ti + (p - st);
    int rowA = k*B + ti*64;
    int rowB = k*B + tj*64;
    int t = threadIdx.x;
    int tx = t & 15, ty = t >> 4;
    float acc[4][4];
    #pragma unroll
    for (int i=0;i<4;i++)
        #pragma unroll
        for (int j=0;j<4;j++) acc[i][j]=0.f;

    for (int ch = z; ch*32 < D; ch += 8){
        int dbase = ch*32;
        int valid = D - dbase; if (valid > 32) valid = 32;   // 32 or 16, mult of 4
        #pragma unroll
        for (int f0 = 0; f0 < 512; f0 += 256){
            int f = f0 + t;
            int row = f >> 3, q = f & 7;
            float4 a = make_float4(0,0,0,0), b = make_float4(0,0,0,0);
            if (q*4 < valid){
                a = *(const float4*)&X[(size_t)(rowA + row)*D + dbase + q*4];
                b = *(const float4*)&X[(size_t)(rowB + row)*D + dbase + q*4];
            }
            int pr = row ^ (q<<3);           // swizzled physical col (key = (dd>>2)<<3 = q<<3)
            Asm[q*4+0][pr]=a.x; Asm[q*4+1][pr]=a.y; Asm[q*4+2][pr]=a.z; Asm[q*4+3][pr]=a.w;
            Bsm[q*4+0][pr]=b.x; Bsm[q*4+1][pr]=b.y; Bsm[q*4+2][pr]=b.z; Bsm[q*4+3][pr]=b.w;
        }
        __syncthreads();
        #pragma unroll 4
        for (int dd=0; dd<32; ++dd){
            int sw = ((dd>>2)&7)<<3;
            const float4 av = *(const float4*)&Asm[dd][(ty*4) ^ sw];
            const float4 bv = *(const float4*)&Bsm[dd][(tx*4) ^ sw];
            float a4[4] = {av.x, av.y, av.z, av.w};
            float b4[4] = {bv.x, bv.y, bv.z, bv.w};
            #pragma unroll
            for (int i=0;i<4;i++)
                #pragma unroll
                for (int j=0;j<4;j++) acc[i][j] += a4[i]*b4[j];
        }
        __syncthreads();
    }
    float* G = Gloc + (size_t)k*B*B;
    int abase = ti*64 + ty*4;
    int bbase = tj*64 + tx*4;
    #pragma unroll
    for (int i=0;i<4;i++)
        #pragma unroll
        for (int j=0;j<4;j++)
            atomicAdd(&G[(abase+i)*B + (bbase+j)], acc[i][j]);
}

// ---------------- S[j][c] = am_c . hv_j for 4 samples/WG (+ fused ||hv||^2) ----------------
__global__ __launch_bounds__(256) void s_kernel(const float* __restrict__ am,
        const float* __restrict__ X, float* __restrict__ S, float* __restrict__ hv2, int k){
    int j0 = blockIdx.x*4;                 // 64 WGs x 4 samples
    int gj0 = k*B + j0;
    int t = threadIdx.x;
    const float4* X4 = (const float4*)X;
    const float4* a4 = (const float4*)am;
    float p[4][C]; float px[4];
    #pragma unroll
    for (int r=0;r<4;r++){ px[r]=0.f;
        #pragma unroll
        for (int c=0;c<C;c++) p[r][c]=0.f; }
    for (int d=t; d<D4; d+=256){
        float4 x0 = X4[(size_t)(gj0+0)*D4 + d];
        float4 x1 = X4[(size_t)(gj0+1)*D4 + d];
        float4 x2 = X4[(size_t)(gj0+2)*D4 + d];
        float4 x3 = X4[(size_t)(gj0+3)*D4 + d];
        px[0] += x0.x*x0.x + x0.y*x0.y + x0.z*x0.z + x0.w*x0.w;
        px[1] += x1.x*x1.x + x1.y*x1.y + x1.z*x1.z + x1.w*x1.w;
        px[2] += x2.x*x2.x + x2.y*x2.y + x2.z*x2.z + x2.w*x2.w;
        px[3] += x3.x*x3.x + x3.y*x3.y + x3.z*x3.z + x3.w*x3.w;
        #pragma unroll
        for (int c=0;c<C;c++){
            float4 a = a4[(size_t)c*D4 + d];
            p[0][c] += x0.x*a.x + x0.y*a.y + x0.z*a.z + x0.w*a.w;
            p[1][c] += x1.x*a.x + x1.y*a.y + x1.z*a.z + x1.w*a.w;
            p[2][c] += x2.x*a.x + x2.y*a.y + x2.z*a.z + x2.w*a.w;
            p[3][c] += x3.x*a.x + x3.y*a.y + x3.z*a.z + x3.w*a.w;
        }
    }
    __shared__ float red[4][C+1][4];
    int wid=t>>6, lane=t&63;
    #pragma unroll
    for (int r=0;r<4;r++){
        #pragma unroll
        for (int v=0; v<C+1; ++v){
            float x = (v<C)? p[r][v] : px[r];
            #pragma unroll
            for (int off=32; off>=1; off>>=1) x += __shfl_down(x, off);
            if (lane==0) red[r][v][wid] = x;
        }
    }
    __syncthreads();
    if (t < 4*(C+1)){
        int r = t/(C+1), v = t%(C+1);
        float s = red[r][v][0]+red[r][v][1]+red[r][v][2]+red[r][v][3];
        if (v < C) S[(j0+r)*C + v] = s;
        else hv2[gj0 + r] = s;
    }
}

// ---------------- sequential 256-step replay: single wave, 8-deep G prefetch ----------------
__global__ __launch_bounds__(64) void seq_kernel(const float* __restrict__ S,
        const float* __restrict__ G,        // this block's [256][256] Gram
        const float* __restrict__ hv2, const int* __restrict__ labels,
        float* __restrict__ amnorm2, int* __restrict__ wrongList, int* __restrict__ nwrong,
        int* __restrict__ mistakes, int k){
    int lane = threadIdx.x;
    int base = k*B;
    float s[4][C];
    float h2o[4]; int labo[4];
    #pragma unroll
    for (int q=0;q<4;q++){
        int j = q*64 + lane;
        #pragma unroll
        for (int c=0;c<C;c++) s[q][c] = S[j*C+c];
        h2o[q] = hv2[base + j];
        labo[q] = labels[base + j];
    }
    float an[C], rstd[C];
    #pragma unroll
    for (int c=0;c<C;c++){ an[c] = amnorm2[c]; rstd[c] = rsqrtf(an[c]); }

    int myPred[4], myWrong[4];
    #pragma unroll
    for (int q=0;q<4;q++){ myPred[q]=0; myWrong[q]=0; }

    // 8-deep circular register prefetch of G rows (static slot indexing via unroll)
    float g[8][4];
    #pragma unroll
    for (int r=0;r<8;r++)
        #pragma unroll
        for (int sl=0;sl<4;sl++) g[r][sl] = G[(size_t)r*B + sl*64 + lane];

    #pragma unroll
    for (int q=0;q<4;q++){
        for (int jj8=0; jj8<8; ++jj8){
            #pragma unroll
            for (int u=0; u<8; ++u){
                int jj = jj8*8 + u;
                int j  = q*64 + jj;
                float gcur[4];
                #pragma unroll
                for (int sl=0;sl<4;sl++) gcur[sl] = g[u][sl];
                if (j+8 < B){
                    #pragma unroll
                    for (int sl=0;sl<4;sl++) g[u][sl] = G[(size_t)(j+8)*B + sl*64 + lane];
                }
                // each lane computes the decision for ITS OWN sample from its own registers
                float best = s[q][0]*rstd[0]; int bi=0; float braw = s[q][0];
                #pragma unroll
                for (int c=1;c<C;c++){
                    float v = s[q][c]*rstd[c];
                    if (v>best){best=v;bi=c;braw=s[q][c];}
                }
                int labme = labo[q];
                float slv = s[q][0];
                #pragma unroll
                for (int c=1;c<C;c++) slv = (c==labme)? s[q][c] : slv;
                int wrongme = (bi != labme) ? 1 : 0;
                if (lane == jj){ myPred[q]=bi; myWrong[q]=wrongme; }
                // broadcast owner's decision: 4 shuffles
                int   pk    = __shfl(bi | (labme<<8) | (wrongme<<16), jj);
                float brawB = __shfl(braw, jj);
                float slvB  = __shfl(slv,  jj);
                float h2b   = __shfl(h2o[q], jj);
                int biB = pk & 255, labB = (pk>>8) & 255, wrongB = (pk>>16) & 1;
                if (wrongB){
                    float anp = an[0], anl = an[0];
                    #pragma unroll
                    for (int c=1;c<C;c++){ anp = (c==biB)? an[c]:anp; anl = (c==labB)? an[c]:anl; }
                    float anp_new = anp - 2.f*brawB + h2b;   // ||am_pred - hv||^2
                    float anl_new = anl + 2.f*slvB  + h2b;   // ||am_lab  + hv||^2
                    float rp = rsqrtf(anp_new), rl = rsqrtf(anl_new);
                    #pragma unroll
                    for (int c=0;c<C;c++){
                        an[c]   = (c==biB)? anp_new : (c==labB)? anl_new : an[c];
                        rstd[c] = (c==biB)? rp      : (c==labB)? rl      : rstd[c];
                    }
                    #pragma unroll
                    for (int c=0;c<C;c++){
                        float sg = (c==biB)? -1.f : (c==labB)? 1.f : 0.f;
                        #pragma unroll
                        for (int sl=0;sl<4;sl++) s[sl][c] += sg * gcur[sl];
                    }
                }
            }
        }
    }
    // compact wrong list: packed j | pred<<8 | lab<<12
    int ofs = 0;
    #pragma unroll
    for (int q=0;q<4;q++){
        unsigned long long m = __ballot(myWrong[q] != 0);
        if (myWrong[q]){
            int pos = ofs + __popcll(m & ((1ull<<lane)-1ull));
            wrongList[base + pos] = (q*64+lane) | (myPred[q]<<8) | (labo[q]<<12);
        }
        ofs += __popcll(m);
    }
    if (lane==0){
        nwrong[k] = ofs;
        atomicAdd(mistakes, ofs);
        #pragma unroll
        for (int c=0;c<C;c++) amnorm2[c] = an[c];
    }
}

// ---------------- fold corrections into am: compacted wrong-list, sliced, atomic finish ----
__global__ __launch_bounds__(256) void apply_kernel(float* __restrict__ am,
        const float* __restrict__ X, const int* __restrict__ wrongList,
        const int* __restrict__ nwrong, int k){
    int d4 = blockIdx.x*256 + threadIdx.x;
    if (d4 >= D4) return;
    int cnt = nwrong[k];
    int slice = blockIdx.y;                 // 0..3
    if (slice >= cnt) return;               // fast exit when few/no wrongs
    const float4* X4 = (const float4*)X;
    float4 delta[C];
    #pragma unroll
    for (int c=0;c<C;c++) delta[c] = make_float4(0.f,0.f,0.f,0.f);
    int touched = 0;
    for (int w = slice; w < cnt; w += 4){
        int pk = wrongList[k*B + w];        // uniform scalar load
        int j = pk & 255, pcl = (pk>>8)&15, lcl = (pk>>12)&15;
        touched |= (1<<pcl) | (1<<lcl);
        float4 x = X4[(size_t)(k*B + j)*D4 + d4];
        #pragma unroll
        for (int c=0;c<C;c++){              // static indexing (rule #20)
            float coef = ((c==pcl)? -1.f : 0.f) + ((c==lcl)? 1.f : 0.f);
            delta[c].x += coef*x.x; delta[c].y += coef*x.y;
            delta[c].z += coef*x.z; delta[c].w += coef*x.w;
        }
    }
    #pragma unroll
    for (int c=0;c<C;c++){
        if (touched & (1<<c)){              // wave-uniform
            float* p = &am[(size_t)c*D + d4*4];
            atomicAdd(p+0, delta[c].x); atomicAdd(p+1, delta[c].y);
            atomicAdd(p+2, delta[c].z); atomicAdd(p+3, delta[c].w);
        }
    }
}

// ---------------- final predict: 4 rows/WG, float4, am reuse in registers ----------------
__global__ __launch_bounds__(256) void predict_kernel(const float* __restrict__ am,
        const float* __restrict__ X, const float* __restrict__ anf, float* __restrict__ outPred){
    int i0 = blockIdx.x*4, t = threadIdx.x;
    const float4* a4 = (const float4*)am;
    const float4* X4 = (const float4*)X;
    float p[4][C];
    #pragma unroll
    for (int r=0;r<4;r++)
        #pragma unroll
        for (int c=0;c<C;c++) p[r][c]=0.f;
    for (int d=t; d<D4; d+=256){
        float4 x0 = X4[(size_t)(i0+0)*D4 + d];
        float4 x1 = X4[(size_t)(i0+1)*D4 + d];
        float4 x2 = X4[(size_t)(i0+2)*D4 + d];
        float4 x3 = X4[(size_t)(i0+3)*D4 + d];
        #pragma unroll
        for (int c=0;c<C;c++){
            float4 a = a4[(size_t)c*D4 + d];
            p[0][c] += x0.x*a.x + x0.y*a.y + x0.z*a.z + x0.w*a.w;
            p[1][c] += x1.x*a.x + x1.y*a.y + x1.z*a.z + x1.w*a.w;
            p[2][c] += x2.x*a.x + x2.y*a.y + x2.z*a.z + x2.w*a.w;
            p[3][c] += x3.x*a.x + x3.y*a.y + x3.z*a.z + x3.w*a.w;
        }
    }
    __shared__ float red[4][C][4];
    int wid=t>>6, lane=t&63;
    #pragma unroll
    for (int r=0;r<4;r++)
        #pragma unroll
        for (int c=0;c<C;c++){
            float x = p[r][c];
            #pragma unroll
            for (int off=32; off>=1; off>>=1) x += __shfl_down(x, off);
            if (lane==0) red[r][c][wid] = x;
        }
    __syncthreads();
    if (t < 4){
        float best = -3.4e38f; int bi = 0;
        #pragma unroll
        for (int c=0;c<C;c++){
            float dot = red[t][c][0]+red[t][c][1]+red[t][c][2]+red[t][c][3];
            float v = dot * rsqrtf(anf[c]);
            if (v > best){ best = v; bi = c; }
        }
        outPred[i0 + t] = (float)bi;
    }
}

// ---------------- am copy + mistakes scalar ----------------
__global__ __launch_bounds__(256) void finalize_kernel(const float* __restrict__ am,
        const int* __restrict__ mistakes, float* __restrict__ out){
    int i = blockIdx.x*256 + threadIdx.x;
    if (i < C*D) out[i] = am[i];
    if (i == 0) out[C*D + N] = (float)(*mistakes);
}

extern "C" void kernel_launch(void* const* d_in, const int* in_sizes, int n_in,
                              void* d_out, int out_size, void* d_ws, size_t ws_size,
                              hipStream_t stream){
    const float* X      = (const float*)d_in[0];
    const int*   labels = (const int*)d_in[1];
    float* ws   = (float*)d_ws;
    float* am   = ws + AM_OFF;
    float* Gloc = ws + GLOC_OFF;
    float* S    = ws + S_OFF;
    float* hv2  = ws + HV2_OFF;
    float* an   = ws + AN_OFF;
    float* anf  = ws + ANF_OFF;
    int*   wlist  = (int*)(ws + WLIST_OFF);
    int*   nwrong = (int*)(ws + NWRONG_OFF);
    int*   mist   = (int*)(ws + MIST_OFF);
    float* out = (float*)d_out;

    hipMemsetAsync(am,   0, (size_t)C*D*sizeof(float), stream);
    hipMemsetAsync(Gloc, 0, (size_t)NB*B*B*sizeof(float), stream);
    hipMemsetAsync(mist, 0, sizeof(int), stream);

    build_am_kernel<<<dim3(10,16), 256, 0, stream>>>(am, X, labels);
    rownorm2_kernel<<<C, 256, 0, stream>>>(am, an);
    gram_kernel<<<dim3(80,NB), 256, 0, stream>>>(X, Gloc);

    for (int k=0;k<NB;k++){
        s_kernel<<<64, 256, 0, stream>>>(am, X, S, hv2, k);
        seq_kernel<<<1, 64, 0, stream>>>(S, Gloc + (size_t)k*B*B, hv2, labels,
                                         an, wlist, nwrong, mist, k);
        apply_kernel<<<dim3(10,4), 256, 0, stream>>>(am, X, wlist, nwrong, k);
    }

    rownorm2_kernel<<<C, 256, 0, stream>>>(am, anf);
    predict_kernel<<<N/4, 256, 0, stream>>>(am, X, anf, out + (size_t)C*D);
    finalize_kernel<<<(C*D + 255)/256 + 1, 256, 0, stream>>>(am, mist, out);
}